// Round 7
// baseline (97.091 us; speedup 1.0000x reference)
//
#include <hip/hip_runtime.h>
#include <hip/hip_bf16.h>

// ModConv2d: per-sample modulated 3x3 conv (N=8, C=64->64, 256x256) + MLPs.
// Kernel 1: MLPs -> w_bf[n][kidx][cb][cout][8ci] (bf16, A-frag 16B units) + bias.
// Kernel 2: implicit-GEMM conv, builtin mfma_f32_32x32x16_bf16.
//   Block: 512 thr (8 waves), 4 output rows x 256 cols x 64 couts. Grid 512.
//   Wave (wr, wh): row h0+wr, col half wh*128; acc[2][4] = 128 AGPR;
//   per kidx: 2 A-reads + 4 B-reads -> 8 MFMA (0.75 ds_read/MFMA).
//   x LDS: [6 rows][2 half][258][16B] dbuf = 99 KB. Weights: per-16ci-chunk
//   slice (9 kidx x 2 cb x 64 cout = 18.4 KB) dbuf'd, register-staged with
//   full-chunk vmcnt cover. Total LDS 135.9 KB. 1 barrier per chunk.
//   x staging: 2-deep st pipeline, ISSUE@kidx{0,2,4}, WRITE@kidx{2,4,6}.

typedef short bf16x8 __attribute__((ext_vector_type(8)));
typedef float f32x16 __attribute__((ext_vector_type(16)));

#define NB 8
#define CIN 64
#define COUT 64
#define HH 256
#define WW 256
#define HWP (HH * WW)
#define AUXD 128
#define HIDD 256

#define XH 4128                 // half-ci plane: 258 * 16B
#define XRW (2 * XH)            // staged row: 8256 B
#define XBUF (6 * XRW)          // 49536 B
#define WOFF0 (2 * XBUF)        // 99072
#define WCH (9 * 2 * 64 * 16)   // 18432 B per weight chunk
#define SMEMB (WOFF0 + 2 * WCH) // 135936

__device__ __forceinline__ unsigned short f2bf(float f) {
    unsigned u = __builtin_bit_cast(unsigned, f);
    u += 0x7FFFu + ((u >> 16) & 1u);   // RNE
    return (unsigned short)(u >> 16);
}

__device__ __forceinline__ unsigned pk2(float a, float b, float vm) {
    return (unsigned)f2bf(a * vm) | ((unsigned)f2bf(b * vm) << 16);
}

// ---------------- Kernel 1: MLPs ----------------
__global__ __launch_bounds__(256) void mlp_kernel(
    const float* __restrict__ y, const float* __restrict__ weight,
    const float* __restrict__ fc_w1, const float* __restrict__ fc_b1,
    const float* __restrict__ fc_prelu,
    const float* __restrict__ fc_w2, const float* __restrict__ fc_b2,
    const float* __restrict__ bias_w1, const float* __restrict__ bias_b1,
    const float* __restrict__ bias_prelu,
    const float* __restrict__ bias_w2, const float* __restrict__ bias_b2,
    unsigned short* __restrict__ w_bf, float* __restrict__ bvec)
{
    const int n = blockIdx.y;
    const int c = blockIdx.x;
    const int tid = threadIdx.x;
    __shared__ float ylds[AUXD];
    __shared__ float hl[HIDD];
    if (tid < AUXD) ylds[tid] = y[n * AUXD + tid];
    __syncthreads();

    if (c < 16) {
        float s = fc_b1[tid];
        const float* wrow = fc_w1 + tid * AUXD;
        #pragma unroll 4
        for (int a = 0; a < AUXD; ++a) s += ylds[a] * wrow[a];
        float ap = fc_prelu[0];
        hl[tid] = s >= 0.f ? s : ap * s;
        __syncthreads();

        int o = c * 256 + tid;           // o = cout*64 + ci
        float t = fc_b2[o];
        const float* w2row = fc_w2 + o * HIDD;
        #pragma unroll 4
        for (int h = 0; h < HIDD; ++h) t += hl[h] * w2row[h];
        float mod = 1.f / (1.f + expf(-t));
        int cout = o >> 6, ci = o & 63;
        int cb = ci >> 3, cl = ci & 7;
        #pragma unroll
        for (int k = 0; k < 9; ++k) {
            float wv = weight[o * 9 + k];
            // 16B unit = ((n*9+k)*8 + cb)*64 + cout; halfword cl
            w_bf[((((n * 9 + k) * 8 + cb) * 64 + cout) << 3) + cl] = f2bf(mod * wv);
        }
    } else {
        float s = bias_b1[tid];
        const float* wrow = bias_w1 + tid * AUXD;
        #pragma unroll 4
        for (int a = 0; a < AUXD; ++a) s += ylds[a] * wrow[a];
        float ap = bias_prelu[0];
        hl[tid] = s >= 0.f ? s : ap * s;
        __syncthreads();
        if (tid < COUT) {
            float t = bias_b2[tid];
            const float* w2row = bias_w2 + tid * HIDD;
            #pragma unroll 4
            for (int h = 0; h < HIDD; ++h) t += hl[h] * w2row[h];
            bvec[n * COUT + tid] = t;
        }
    }
}

// ---------------- Kernel 2: conv ----------------
// x staging: load 16 ci-planes for one row into named st regs / write to LDS
#define ISSUE(stv, k, ci0) { _Pragma("unroll") \
    for (int i = 0; i < 16; ++i) stv[i] = xr[k][(size_t)((ci0) + i) * HWP]; }

#define WRX(stv, k, buf) { float vm = vmr[k]; \
    unsigned char* dst = (buf) + (rg + 2 * (k)) * XRW + (sw + 1) * 16; \
    uint4 lo, hi; \
    lo.x = pk2(stv[0], stv[1], vm);  lo.y = pk2(stv[2], stv[3], vm); \
    lo.z = pk2(stv[4], stv[5], vm);  lo.w = pk2(stv[6], stv[7], vm); \
    hi.x = pk2(stv[8], stv[9], vm);  hi.y = pk2(stv[10], stv[11], vm); \
    hi.z = pk2(stv[12], stv[13], vm); hi.w = pk2(stv[14], stv[15], vm); \
    *(uint4*)dst = lo; *(uint4*)(dst + XH) = hi; }

// weight-chunk staging (1152 16B units; 512 threads -> 3 iters, last partial)
#define WCHLOAD(cc) { _Pragma("unroll") \
    for (int it = 0; it < 3; ++it) { int u = it * 512 + tid; \
        if (u < 1152) wA[it] = wsrc[(cc) * 128 + ((u >> 7) << 9) + (u & 127)]; } }

#define WCHSTORE(pp) { unsigned char* wd = smem + WOFF0 + (pp) * WCH; \
    _Pragma("unroll") \
    for (int it = 0; it < 3; ++it) { int u = it * 512 + tid; \
        if (u < 1152) *(uint4*)(wd + (u << 4)) = wA[it]; } }

__global__ __launch_bounds__(512, 2) void conv_kernel(
    const float* __restrict__ x, const unsigned short* __restrict__ w_bf,
    const float* __restrict__ bvec, float* __restrict__ out)
{
    __shared__ __align__(16) unsigned char smem[SMEMB];

    const int bid = blockIdx.x;
    const int n = bid & 7;              // sample -> XCD (x/weights L2 locality)
    const int h0 = (bid >> 3) * 4;      // first output row

    const int tid = threadIdx.x;
    const int lane = tid & 63;
    const int wave = tid >> 6;
    const int wr = wave >> 1;           // output row 0..3
    const int wh = wave & 1;            // col half
    const int l5 = lane >> 5;           // K half
    const int l31 = lane & 31;

    const int sw = tid & 255;           // staging col
    const int rg = tid >> 8;            // 0..1; stages rows rg, rg+2, rg+4

    // staging row pointers (clamped + zero mask at image edges)
    const float* xr[3];
    float vmr[3];
    #pragma unroll
    for (int k = 0; k < 3; ++k) {
        int r = rg + 2 * k;
        int hin = h0 - 1 + r;
        bool val = (hin >= 0) && (hin < HH);
        xr[k] = x + (size_t)n * CIN * HWP + (size_t)(val ? hin : 0) * WW + sw;
        vmr[k] = val ? 1.f : 0.f;
    }

    const uint4* wsrc = (const uint4*)w_bf + (size_t)n * (9 * 8 * 64);
    uint4 wA[3];

    // zero halo entries (w-index 0 and 257): 6 rows x 2 halves x 2 sides x 2 bufs
    if (tid < 48) {
        int hf = tid & 1, side = (tid >> 1) & 1, r = (tid >> 2) % 6, buf = tid / 24;
        uint4 z; z.x = z.y = z.z = z.w = 0u;
        *(uint4*)(smem + buf * XBUF + r * XRW + hf * XH + (side ? 257 : 0) * 16) = z;
    }

    // prologue: weights chunk 0 + x chunk 0 (3 rows, serial) into buf 0
    WCHLOAD(0);
    {
        float stA[16];
        ISSUE(stA, 0, 0); WRX(stA, 0, smem);
        ISSUE(stA, 1, 0); WRX(stA, 1, smem);
        ISSUE(stA, 2, 0); WRX(stA, 2, smem);
    }
    WCHSTORE(0);

    // acc init = per-cout bias (D row = (reg&3) + 8*(reg>>2) + 4*l5)
    f32x16 acc[2][4];
    #pragma unroll
    for (int m = 0; m < 2; ++m) {
        #pragma unroll
        for (int reg = 0; reg < 16; ++reg)
            acc[m][0][reg] = bvec[n * COUT + m * 32 + (reg & 3) + 8 * (reg >> 2) + 4 * l5];
        #pragma unroll
        for (int j = 1; j < 4; ++j) acc[m][j] = acc[m][0];
    }

    __syncthreads();

    float stA[16], stB[16];
    for (int c = 0; c < 4; ++c) {
        const int p = c & 1;
        const unsigned char* rbuf = smem + p * XBUF;
        const unsigned char* wb = smem + WOFF0 + p * WCH;
        unsigned char* nx = smem + (p ^ 1) * XBUF;
        const bool more = (c < 3);
        const int nci = (c + 1) * 16;

        if (more) WCHLOAD(c + 1);   // full-chunk vmcnt cover

        #pragma unroll
        for (int kidx = 0; kidx < 9; ++kidx) {
            const int kh = kidx / 3, kw = kidx % 3;
            // A-frags: lane holds A[cout = m*32+l31][k = 8*l5 + j]
            const unsigned char* ab = wb + (((kidx * 2 + l5) * 64 + l31) << 4);
            bf16x8 aA = *(const bf16x8*)ab;
            bf16x8 aB = *(const bf16x8*)(ab + 512);

            if (more) {
                if (kidx == 0)      { ISSUE(stA, 0, nci); }
                else if (kidx == 2) { WRX(stA, 0, nx); ISSUE(stB, 1, nci); }
                else if (kidx == 4) { WRX(stB, 1, nx); ISSUE(stA, 2, nci); }
                else if (kidx == 6) { WRX(stA, 2, nx); }
                else if (kidx == 7) { WCHSTORE(p ^ 1); }
            }

            // B-frags: lane holds B[k = 8*l5+j][col = l31] = x[wr+kh][col+kw]
            const unsigned char* bb = rbuf + (wr + kh) * XRW + l5 * XH;
            #pragma unroll
            for (int j = 0; j < 4; ++j) {
                bf16x8 b0 = *(const bf16x8*)(bb + (wh * 128 + j * 32 + l31 + kw) * 16);
                acc[0][j] = __builtin_amdgcn_mfma_f32_32x32x16_bf16(aA, b0, acc[0][j], 0, 0, 0);
                acc[1][j] = __builtin_amdgcn_mfma_f32_32x32x16_bf16(aB, b0, acc[1][j], 0, 0, 0);
            }
        }
        __syncthreads();
    }

    // epilogue: D col = l31, row = (reg&3) + 8*(reg>>2) + 4*l5
    const int hout = h0 + wr;
    float* ob = out + ((size_t)n * COUT * HH + hout) * WW;
    #pragma unroll
    for (int m = 0; m < 2; ++m) {
        #pragma unroll
        for (int j = 0; j < 4; ++j) {
            int colb = wh * 128 + j * 32 + l31;
            #pragma unroll
            for (int reg = 0; reg < 16; ++reg) {
                int cout = m * 32 + (reg & 3) + 8 * (reg >> 2) + 4 * l5;
                ob[(size_t)cout * HWP + colb] = acc[m][j][reg];
            }
        }
    }
}

extern "C" void kernel_launch(void* const* d_in, const int* in_sizes, int n_in,
                              void* d_out, int out_size, void* d_ws, size_t ws_size,
                              hipStream_t stream) {
    const float* x          = (const float*)d_in[0];
    const float* y          = (const float*)d_in[1];
    const float* weight     = (const float*)d_in[2];
    const float* fc_w1      = (const float*)d_in[3];
    const float* fc_b1      = (const float*)d_in[4];
    const float* fc_prelu   = (const float*)d_in[5];
    const float* fc_w2      = (const float*)d_in[6];
    const float* fc_b2      = (const float*)d_in[7];
    const float* bias_w1    = (const float*)d_in[8];
    const float* bias_b1    = (const float*)d_in[9];
    const float* bias_prelu = (const float*)d_in[10];
    const float* bias_w2    = (const float*)d_in[11];
    const float* bias_b2    = (const float*)d_in[12];
    float* out = (float*)d_out;

    unsigned short* w_bf = (unsigned short*)d_ws;                       // 589824 B
    float* bvec = (float*)((char*)d_ws + (size_t)NB * 9 * 64 * 64 * 2); // 2048 B

    hipLaunchKernelGGL(mlp_kernel, dim3(17, 8), dim3(256), 0, stream,
                       y, weight, fc_w1, fc_b1, fc_prelu, fc_w2, fc_b2,
                       bias_w1, bias_b1, bias_prelu, bias_w2, bias_b2, w_bf, bvec);
    hipLaunchKernelGGL(conv_kernel, dim3(512), dim3(512), 0, stream,
                       x, w_bf, bvec, out);
}

// Round 8
// 95.847 us; speedup vs baseline: 1.0130x; 1.0130x over previous
//
#include <hip/hip_runtime.h>
#include <hip/hip_bf16.h>

// ModConv2d: per-sample modulated 3x3 conv (N=8, C=64->64, 256x256) + MLPs.
// Kernel 1: MLPs -> w_bf[n][kidx][cb][cout][8ci] (bf16, A-frag 16B units) + bias.
// Kernel 2: implicit-GEMM conv, builtin mfma_f32_32x32x16_bf16, 8-ci chunks:
//   K=16 step = kidx-pair (l5 half selects kidxA/kidxB), 5 pairs/chunk, pair 4
//   pads the odd kidx 8 with a zero A-slot. 8 chunks of 8 ci.
//   Block: 512 thr (8 waves), 2 output rows x 256 cols x 64 couts; grid 1024.
//   Wave (wr, wq): row, 64-col quarter; acc[2][2] = 64 AGPR, r/m = 1.0.
//   LDS 51.5 KB total (x [4][258][16B] dbuf + w-slice [9*64+pad] dbuf)
//   + launch_bounds(512,4) -> 2 blocks/CU, 4 waves/SIMD: blocks hide each
//   other's prologue/epilogue/barrier drains. Staging issued 1 chunk ahead.

typedef short bf16x8 __attribute__((ext_vector_type(8)));
typedef float f32x16 __attribute__((ext_vector_type(16)));

#define NB 8
#define CIN 64
#define COUT 64
#define HH 256
#define WW 256
#define HWP (HH * WW)
#define AUXD 128
#define HIDD 256

#define XRW8 (258 * 16)          // 4128 B: one row-plane (8 ci)
#define XBUF (4 * XRW8)          // 16512 B
#define WOFF0 (2 * XBUF)         // 33024
#define WSLOT ((9 * 64 + 1) * 16) // 9232 B per weight buffer (576 units + zero)
#define SMEMB (WOFF0 + 2 * WSLOT) // 51488

__device__ __forceinline__ unsigned short f2bf(float f) {
    unsigned u = __builtin_bit_cast(unsigned, f);
    u += 0x7FFFu + ((u >> 16) & 1u);   // RNE
    return (unsigned short)(u >> 16);
}

__device__ __forceinline__ unsigned pk2(float a, float b, float vm) {
    return (unsigned)f2bf(a * vm) | ((unsigned)f2bf(b * vm) << 16);
}

// ---------------- Kernel 1: MLPs ----------------
__global__ __launch_bounds__(256) void mlp_kernel(
    const float* __restrict__ y, const float* __restrict__ weight,
    const float* __restrict__ fc_w1, const float* __restrict__ fc_b1,
    const float* __restrict__ fc_prelu,
    const float* __restrict__ fc_w2, const float* __restrict__ fc_b2,
    const float* __restrict__ bias_w1, const float* __restrict__ bias_b1,
    const float* __restrict__ bias_prelu,
    const float* __restrict__ bias_w2, const float* __restrict__ bias_b2,
    unsigned short* __restrict__ w_bf, float* __restrict__ bvec)
{
    const int n = blockIdx.y;
    const int c = blockIdx.x;
    const int tid = threadIdx.x;
    __shared__ float ylds[AUXD];
    __shared__ float hl[HIDD];
    if (tid < AUXD) ylds[tid] = y[n * AUXD + tid];
    __syncthreads();

    if (c < 16) {
        float s = fc_b1[tid];
        const float* wrow = fc_w1 + tid * AUXD;
        #pragma unroll 4
        for (int a = 0; a < AUXD; ++a) s += ylds[a] * wrow[a];
        float ap = fc_prelu[0];
        hl[tid] = s >= 0.f ? s : ap * s;
        __syncthreads();

        int o = c * 256 + tid;           // o = cout*64 + ci
        float t = fc_b2[o];
        const float* w2row = fc_w2 + o * HIDD;
        #pragma unroll 4
        for (int h = 0; h < HIDD; ++h) t += hl[h] * w2row[h];
        float mod = 1.f / (1.f + expf(-t));
        int cout = o >> 6, ci = o & 63;
        int cb = ci >> 3, cl = ci & 7;
        #pragma unroll
        for (int k = 0; k < 9; ++k) {
            float wv = weight[o * 9 + k];
            // 16B unit = ((n*9+k)*8 + cb)*64 + cout; halfword cl
            w_bf[((((n * 9 + k) * 8 + cb) * 64 + cout) << 3) + cl] = f2bf(mod * wv);
        }
    } else {
        float s = bias_b1[tid];
        const float* wrow = bias_w1 + tid * AUXD;
        #pragma unroll 4
        for (int a = 0; a < AUXD; ++a) s += ylds[a] * wrow[a];
        float ap = bias_prelu[0];
        hl[tid] = s >= 0.f ? s : ap * s;
        __syncthreads();
        if (tid < COUT) {
            float t = bias_b2[tid];
            const float* w2row = bias_w2 + tid * HIDD;
            #pragma unroll 4
            for (int h = 0; h < HIDD; ++h) t += hl[h] * w2row[h];
            bvec[n * COUT + tid] = t;
        }
    }
}

// ---------------- Kernel 2: conv ----------------
// x staging: 8 ci-planes of one row -> 8 f32 regs -> one 16B LDS entry
#define XISSUE(stv, k, ci0) { _Pragma("unroll") \
    for (int i = 0; i < 8; ++i) stv[i] = xr[k][(size_t)((ci0) + i) * HWP]; }

#define XWRITE(stv, k, buf) { float vm = vmr[k]; uint4 v; \
    v.x = pk2(stv[0], stv[1], vm); v.y = pk2(stv[2], stv[3], vm); \
    v.z = pk2(stv[4], stv[5], vm); v.w = pk2(stv[6], stv[7], vm); \
    *(uint4*)((buf) + (rg + 2 * (k)) * XRW8 + (sw + 1) * 16) = v; }

// weight slice for chunk cc: units [kidx 0..8][cout 0..63] (576 x 16B)
#define WLOAD(cc) { wv0 = wsrc[((tid >> 6) << 9) + (cc) * 64 + (tid & 63)]; \
    if (tid < 64) wv1 = wsrc[4096 + (cc) * 64 + tid]; }

#define WSTORE(pp) { unsigned char* wd = smem + WOFF0 + (pp) * WSLOT; \
    *(uint4*)(wd + (tid << 4)) = wv0; \
    if (tid < 64) *(uint4*)(wd + ((512 + tid) << 4)) = wv1; }

__global__ __launch_bounds__(512, 4) void conv_kernel(
    const float* __restrict__ x, const unsigned short* __restrict__ w_bf,
    const float* __restrict__ bvec, float* __restrict__ out)
{
    __shared__ __align__(16) unsigned char smem[SMEMB];

    const int bid = blockIdx.x;
    const int n = bid & 7;              // sample -> XCD (x/weights L2 locality)
    const int h0 = (bid >> 3) * 2;      // first output row

    const int tid = threadIdx.x;
    const int lane = tid & 63;
    const int wave = tid >> 6;
    const int wr = wave >> 2;           // output row 0..1
    const int wq = wave & 3;            // 64-col quarter
    const int l5 = lane >> 5;           // K half (selects kidx of the pair)
    const int l31 = lane & 31;

    const int sw = tid & 255;           // staging col
    const int rg = tid >> 8;            // 0..1; stages rows rg, rg+2

    // staging row pointers (clamped + zero mask at image edges)
    const float* xr[2];
    float vmr[2];
    #pragma unroll
    for (int k = 0; k < 2; ++k) {
        int r = rg + 2 * k;
        int hin = h0 - 1 + r;
        bool val = (hin >= 0) && (hin < HH);
        xr[k] = x + (size_t)n * CIN * HWP + (size_t)(val ? hin : 0) * WW + sw;
        vmr[k] = val ? 1.f : 0.f;
    }

    const uint4* wsrc = (const uint4*)w_bf + (size_t)n * (9 * 8 * 64);
    uint4 wv0, wv1;

    // zero halo entries (w-index 0 and 257): 2 bufs x 4 rows x 2 sides
    if (tid < 16) {
        int buf = tid >> 3, r = (tid >> 1) & 3, side = tid & 1;
        uint4 z; z.x = z.y = z.z = z.w = 0u;
        *(uint4*)(smem + buf * XBUF + r * XRW8 + (side ? 257 : 0) * 16) = z;
    }
    // zero A-pad slot in both weight buffers
    if (tid >= 16 && tid < 18) {
        uint4 z; z.x = z.y = z.z = z.w = 0u;
        *(uint4*)(smem + WOFF0 + (tid - 16) * WSLOT + 576 * 16) = z;
    }

    // prologue: weights chunk 0; x chunk 0 (both rows); x row0 of chunk 1
    float stA[8], stB[8];
    WLOAD(0);
    XISSUE(stA, 0, 0); XWRITE(stA, 0, smem);
    XISSUE(stB, 1, 0); XWRITE(stB, 1, smem);
    WSTORE(0);
    XISSUE(stA, 0, 8);   // in flight across all of chunk 0

    // acc init = per-cout bias (D row = (reg&3) + 8*(reg>>2) + 4*l5)
    f32x16 acc[2][2];
    #pragma unroll
    for (int m = 0; m < 2; ++m) {
        #pragma unroll
        for (int reg = 0; reg < 16; ++reg)
            acc[m][0][reg] = bvec[n * COUT + m * 32 + (reg & 3) + 8 * (reg >> 2) + 4 * l5];
        acc[m][1] = acc[m][0];
    }

    __syncthreads();

    for (int c = 0; c < 8; ++c) {
        const int p = c & 1;
        const unsigned char* rbuf = smem + p * XBUF;
        const unsigned char* wb = smem + WOFF0 + p * WSLOT;
        unsigned char* nx = smem + (p ^ 1) * XBUF;
        const bool more = (c < 7);

        #pragma unroll
        for (int s = 0; s < 5; ++s) {
            const int ka = 2 * s;                     // 0,2,4,6,8
            const int kb = (s == 4) ? 8 : 2 * s + 1;  // pad pair at s=4
            const int khA = ka / 3, kwA = ka % 3;
            const int khB = kb / 3, kwB = kb % 3;
            const bool solo = (s == 4);

            // A-frags: lane holds A[cout = m*32+l31][k = 8*l5 + j];
            // k<8 -> kidx ka ci j, k>=8 -> kidx kb ci j. Pad lanes read zero slot.
            int au = (solo && l5) ? 576 : ((l5 ? kb : ka) * 64 + l31);
            int am = (solo && l5) ? 0 : 32;
            bf16x8 aA = *(const bf16x8*)(wb + (au << 4));
            bf16x8 aB = *(const bf16x8*)(wb + ((au + am) << 4));

            // B-frags: lane holds B[k][col=l31] = x[wr+kh][col+kw] (8 ci entry)
            int kh = l5 ? khB : khA;
            int kw = l5 ? kwB : kwA;
            const unsigned char* bb = rbuf + (wr + kh) * XRW8;
            bf16x8 b0 = *(const bf16x8*)(bb + ((wq * 64 + l31 + kw) << 4));
            bf16x8 b1 = *(const bf16x8*)(bb + ((wq * 64 + 32 + l31 + kw) << 4));

            // staging interleave (writes go to the other buffer)
            if (s == 0 && more) { WLOAD(c + 1); }
            if (s == 1 && more) { XWRITE(stA, 0, nx); XISSUE(stB, 1, (c + 1) * 8); }
            if (s == 3 && more) { XWRITE(stB, 1, nx);
                                  if (c < 6) { XISSUE(stA, 0, (c + 2) * 8); } }
            if (s == 4 && more) { WSTORE(p ^ 1); }

            acc[0][0] = __builtin_amdgcn_mfma_f32_32x32x16_bf16(aA, b0, acc[0][0], 0, 0, 0);
            acc[0][1] = __builtin_amdgcn_mfma_f32_32x32x16_bf16(aA, b1, acc[0][1], 0, 0, 0);
            acc[1][0] = __builtin_amdgcn_mfma_f32_32x32x16_bf16(aB, b0, acc[1][0], 0, 0, 0);
            acc[1][1] = __builtin_amdgcn_mfma_f32_32x32x16_bf16(aB, b1, acc[1][1], 0, 0, 0);
        }
        __syncthreads();
    }

    // epilogue: D col = l31, row = (reg&3) + 8*(reg>>2) + 4*l5
    const int hout = h0 + wr;
    float* ob = out + ((size_t)n * COUT * HH + hout) * WW;
    #pragma unroll
    for (int m = 0; m < 2; ++m) {
        #pragma unroll
        for (int j = 0; j < 2; ++j) {
            int colb = wq * 64 + j * 32 + l31;
            #pragma unroll
            for (int reg = 0; reg < 16; ++reg) {
                int cout = m * 32 + (reg & 3) + 8 * (reg >> 2) + 4 * l5;
                ob[(size_t)cout * HWP + colb] = acc[m][j][reg];
            }
        }
    }
}

extern "C" void kernel_launch(void* const* d_in, const int* in_sizes, int n_in,
                              void* d_out, int out_size, void* d_ws, size_t ws_size,
                              hipStream_t stream) {
    const float* x          = (const float*)d_in[0];
    const float* y          = (const float*)d_in[1];
    const float* weight     = (const float*)d_in[2];
    const float* fc_w1      = (const float*)d_in[3];
    const float* fc_b1      = (const float*)d_in[4];
    const float* fc_prelu   = (const float*)d_in[5];
    const float* fc_w2      = (const float*)d_in[6];
    const float* fc_b2      = (const float*)d_in[7];
    const float* bias_w1    = (const float*)d_in[8];
    const float* bias_b1    = (const float*)d_in[9];
    const float* bias_prelu = (const float*)d_in[10];
    const float* bias_w2    = (const float*)d_in[11];
    const float* bias_b2    = (const float*)d_in[12];
    float* out = (float*)d_out;

    unsigned short* w_bf = (unsigned short*)d_ws;                       // 589824 B
    float* bvec = (float*)((char*)d_ws + (size_t)NB * 9 * 64 * 64 * 2); // 2048 B

    hipLaunchKernelGGL(mlp_kernel, dim3(17, 8), dim3(256), 0, stream,
                       y, weight, fc_w1, fc_b1, fc_prelu, fc_w2, fc_b2,
                       bias_w1, bias_b1, bias_prelu, bias_w2, bias_b2, w_bf, bvec);
    hipLaunchKernelGGL(conv_kernel, dim3(1024), dim3(512), 0, stream,
                       x, w_bf, bvec, out);
}

// Round 9
// 87.367 us; speedup vs baseline: 1.1113x; 1.0971x over previous
//
#include <hip/hip_runtime.h>
#include <hip/hip_bf16.h>

// ModConv2d: per-sample modulated 3x3 conv (N=8, C=64->64, 256x256) + MLPs.
// Kernel 1: MLPs -> w_bf[n][kidx][cb][cout][8ci] (bf16, A-frag 16B units) + bias.
// Kernel 2: implicit-GEMM conv, builtin mfma_f32_32x32x16_bf16, 8-ci chunks,
//   kidx-pair K=16 steps (5/chunk, pad pair at s=4 reads zero A-slot).
//   Block: 1024 thr (16 waves), 4 output rows x 256 cols x 64 couts; grid 512.
//   Wave (wr, wq): row, 64-col quarter; acc[2][2] = 64 AGPR, r/m = 1.0.
//   Weights staged ONCE in LDS (73.7 KB); x [6 rows][258][16B] dbuf 49.5 KB.
//   Total LDS 123.3 KB -> 1 block/CU, 4 waves/SIMD.
//   KEY CHANGE (T3/T4): raw s_barrier preceded by lgkmcnt(0) ONLY — staged
//   global loads stay in flight across chunk barriers (no vmcnt(0) drain);
//   compiler emits counted vmcnt at the f2bf consumers. T5 setprio on MFMAs.

typedef short bf16x8 __attribute__((ext_vector_type(8)));
typedef float f32x16 __attribute__((ext_vector_type(16)));

#define NB 8
#define CIN 64
#define COUT 64
#define HH 256
#define WW 256
#define HWP (HH * WW)
#define AUXD 128
#define HIDD 256

#define XRW8 (258 * 16)          // 4128 B: one staged row-plane (8 ci)
#define XBUF8 (6 * XRW8)         // 24768 B per buffer
#define WOFF (2 * XBUF8)         // 49536
#define WUNITS (9 * 8 * 64)      // 4608 16B units
#define SMEMB (WOFF + (WUNITS + 1) * 16)  // 123280

__device__ __forceinline__ unsigned short f2bf(float f) {
    unsigned u = __builtin_bit_cast(unsigned, f);
    u += 0x7FFFu + ((u >> 16) & 1u);   // RNE
    return (unsigned short)(u >> 16);
}

__device__ __forceinline__ unsigned pk2(float a, float b, float vm) {
    return (unsigned)f2bf(a * vm) | ((unsigned)f2bf(b * vm) << 16);
}

// ---------------- Kernel 1: MLPs ----------------
__global__ __launch_bounds__(256) void mlp_kernel(
    const float* __restrict__ y, const float* __restrict__ weight,
    const float* __restrict__ fc_w1, const float* __restrict__ fc_b1,
    const float* __restrict__ fc_prelu,
    const float* __restrict__ fc_w2, const float* __restrict__ fc_b2,
    const float* __restrict__ bias_w1, const float* __restrict__ bias_b1,
    const float* __restrict__ bias_prelu,
    const float* __restrict__ bias_w2, const float* __restrict__ bias_b2,
    unsigned short* __restrict__ w_bf, float* __restrict__ bvec)
{
    const int n = blockIdx.y;
    const int c = blockIdx.x;
    const int tid = threadIdx.x;
    __shared__ float ylds[AUXD];
    __shared__ float hl[HIDD];
    if (tid < AUXD) ylds[tid] = y[n * AUXD + tid];
    __syncthreads();

    if (c < 16) {
        float s = fc_b1[tid];
        const float* wrow = fc_w1 + tid * AUXD;
        #pragma unroll 4
        for (int a = 0; a < AUXD; ++a) s += ylds[a] * wrow[a];
        float ap = fc_prelu[0];
        hl[tid] = s >= 0.f ? s : ap * s;
        __syncthreads();

        int o = c * 256 + tid;           // o = cout*64 + ci
        float t = fc_b2[o];
        const float* w2row = fc_w2 + o * HIDD;
        #pragma unroll 4
        for (int h = 0; h < HIDD; ++h) t += hl[h] * w2row[h];
        float mod = 1.f / (1.f + expf(-t));
        int cout = o >> 6, ci = o & 63;
        int cb = ci >> 3, cl = ci & 7;
        #pragma unroll
        for (int k = 0; k < 9; ++k) {
            float wv = weight[o * 9 + k];
            // 16B unit = ((n*9+k)*8 + cb)*64 + cout; halfword cl
            w_bf[((((n * 9 + k) * 8 + cb) * 64 + cout) << 3) + cl] = f2bf(mod * wv);
        }
    } else {
        float s = bias_b1[tid];
        const float* wrow = bias_w1 + tid * AUXD;
        #pragma unroll 4
        for (int a = 0; a < AUXD; ++a) s += ylds[a] * wrow[a];
        float ap = bias_prelu[0];
        hl[tid] = s >= 0.f ? s : ap * s;
        __syncthreads();
        if (tid < COUT) {
            float t = bias_b2[tid];
            const float* w2row = bias_w2 + tid * HIDD;
            #pragma unroll 4
            for (int h = 0; h < HIDD; ++h) t += hl[h] * w2row[h];
            bvec[n * COUT + tid] = t;
        }
    }
}

// ---------------- Kernel 2: conv ----------------
#define XISSUE(stv, xp, ci0) { _Pragma("unroll") \
    for (int i = 0; i < 8; ++i) stv[i] = (xp)[(size_t)((ci0) + i) * HWP]; }

#define XWRITE(stv, rr, vmv, buf) { uint4 v_; \
    v_.x = pk2(stv[0], stv[1], vmv); v_.y = pk2(stv[2], stv[3], vmv); \
    v_.z = pk2(stv[4], stv[5], vmv); v_.w = pk2(stv[6], stv[7], vmv); \
    *(uint4*)((buf) + (rr) * XRW8 + (w + 1) * 16) = v_; }

__global__ __launch_bounds__(1024, 4) void conv_kernel(
    const float* __restrict__ x, const unsigned short* __restrict__ w_bf,
    const float* __restrict__ bvec, float* __restrict__ out)
{
    __shared__ __align__(16) unsigned char smem[SMEMB];

    const int bid = blockIdx.x;
    const int n = bid & 7;              // sample -> XCD (x/weights L2 locality)
    const int h0 = (bid >> 3) * 4;      // first output row

    const int tid = threadIdx.x;
    const int lane = tid & 63;
    const int wave = tid >> 6;
    const int wr = wave >> 2;           // output row 0..3
    const int wq = wave & 3;            // 64-col quarter
    const int l5 = lane >> 5;           // K half (selects kidx of the pair)
    const int l31 = lane & 31;

    // staging: entry e0 = (row tid>>8, col tid&255); waves 0..7 also e1 (rows 4,5)
    const int w = tid & 255;
    const int r0 = tid >> 8;            // 0..3
    const bool has2 = (tid < 512);
    const int r1 = 4 + (tid >> 8);      // 4..5 when has2

    int hin0 = h0 - 1 + r0;
    bool v0 = (hin0 >= 0) && (hin0 < HH);
    const float vm0 = v0 ? 1.f : 0.f;
    const float* xp0 = x + (size_t)n * CIN * HWP + (size_t)(v0 ? hin0 : 0) * WW + w;
    int hin1 = h0 - 1 + r1;
    bool v1 = (hin1 >= 0) && (hin1 < HH);
    const float vm1 = v1 ? 1.f : 0.f;
    const float* xp1 = x + (size_t)n * CIN * HWP + (size_t)(v1 ? hin1 : 0) * WW + w;

    // ---- prologue: stage ALL weights (once) ----
    {
        const uint4* wsrc = (const uint4*)w_bf + (size_t)n * WUNITS;
        #pragma unroll
        for (int it = 0; it < 5; ++it) {
            int u = it * 1024 + tid;
            if (u < WUNITS) *(uint4*)(smem + WOFF + (u << 4)) = wsrc[u];
        }
    }
    // zero halo entries (w-index 0 and 257): 2 bufs x 6 rows x 2 sides = 24
    if (tid < 24) {
        int buf = tid / 12, rr = (tid % 12) >> 1, side = tid & 1;
        uint4 z; z.x = z.y = z.z = z.w = 0u;
        *(uint4*)(smem + buf * XBUF8 + rr * XRW8 + (side ? 257 : 0) * 16) = z;
    }
    if (tid == 24) {  // zero A-pad unit
        uint4 z; z.x = z.y = z.z = z.w = 0u;
        *(uint4*)(smem + WOFF + (WUNITS << 4)) = z;
    }

    // stage x chunk 0 into buf 0
    float stA[8], stB[8];
    XISSUE(stA, xp0, 0);
    XWRITE(stA, r0, vm0, smem);
    if (has2) { XISSUE(stB, xp1, 0); XWRITE(stB, r1, vm1, smem); }

    // acc init = per-cout bias (D row = (reg&3) + 8*(reg>>2) + 4*l5)
    f32x16 acc[2][2];
    #pragma unroll
    for (int m = 0; m < 2; ++m) {
        #pragma unroll
        for (int reg = 0; reg < 16; ++reg)
            acc[m][0][reg] = bvec[n * COUT + m * 32 + (reg & 3) + 8 * (reg >> 2) + 4 * l5];
        acc[m][1] = acc[m][0];
    }

    asm volatile("s_waitcnt lgkmcnt(0)" ::: "memory");
    __builtin_amdgcn_s_barrier();

    for (int c = 0; c < 8; ++c) {
        const int p = c & 1;
        const unsigned char* rbuf = smem + p * XBUF8;
        unsigned char* nx = smem + (p ^ 1) * XBUF8;
        const bool more = (c < 7);
        const int nci = (c + 1) * 8;

        #pragma unroll
        for (int s = 0; s < 5; ++s) {
            const int ka = 2 * s;                     // 0,2,4,6,8
            const int kb = (s == 4) ? 8 : 2 * s + 1;  // pad pair at s=4
            const bool solo = (s == 4);
            const int khA = ka / 3, kwA = ka % 3;
            const int khB = kb / 3, kwB = kb % 3;
            const int kh = l5 ? khB : khA;
            const int kw = l5 ? kwB : kwA;

            // A-frags: lane holds A[cout = m*32+l31][k = 8*l5 + j]
            int au = (solo && l5) ? WUNITS : ((l5 ? kb : ka) * 8 + c) * 64 + l31;
            int am = (solo && l5) ? 0 : 32;
            bf16x8 aA = *(const bf16x8*)(smem + WOFF + (au << 4));
            bf16x8 aB = *(const bf16x8*)(smem + WOFF + ((au + am) << 4));

            // B-frags: lane holds B[k][col = l31] = x[wr+kh][col+kw]
            const unsigned char* bb = rbuf + (wr + kh) * XRW8;
            bf16x8 b0 = *(const bf16x8*)(bb + ((wq * 64 + l31 + kw) << 4));
            bf16x8 b1 = *(const bf16x8*)(bb + ((wq * 64 + 32 + l31 + kw) << 4));

            // staging interleave: issue early (s0/s1), write late (s3/s4).
            // Loads stay in flight across the raw barrier (no vmcnt drain).
            if (more) {
                if (s == 0)              { XISSUE(stA, xp0, nci); }
                else if (s == 1 && has2) { XISSUE(stB, xp1, nci); }
                else if (s == 3)         { XWRITE(stA, r0, vm0, nx); }
                else if (s == 4 && has2) { XWRITE(stB, r1, vm1, nx); }
            }

            __builtin_amdgcn_s_setprio(1);
            acc[0][0] = __builtin_amdgcn_mfma_f32_32x32x16_bf16(aA, b0, acc[0][0], 0, 0, 0);
            acc[0][1] = __builtin_amdgcn_mfma_f32_32x32x16_bf16(aA, b1, acc[0][1], 0, 0, 0);
            acc[1][0] = __builtin_amdgcn_mfma_f32_32x32x16_bf16(aB, b0, acc[1][0], 0, 0, 0);
            acc[1][1] = __builtin_amdgcn_mfma_f32_32x32x16_bf16(aB, b1, acc[1][1], 0, 0, 0);
            __builtin_amdgcn_s_setprio(0);
        }

        // end-of-chunk: drain LDS ops only; global loads stay outstanding
        asm volatile("s_waitcnt lgkmcnt(0)" ::: "memory");
        __builtin_amdgcn_s_barrier();
    }

    // epilogue: D col = l31, row = (reg&3) + 8*(reg>>2) + 4*l5
    const int hout = h0 + wr;
    float* ob = out + ((size_t)n * COUT * HH + hout) * WW;
    #pragma unroll
    for (int m = 0; m < 2; ++m) {
        #pragma unroll
        for (int j = 0; j < 2; ++j) {
            int colb = wq * 64 + j * 32 + l31;
            #pragma unroll
            for (int reg = 0; reg < 16; ++reg) {
                int cout = m * 32 + (reg & 3) + 8 * (reg >> 2) + 4 * l5;
                ob[(size_t)cout * HWP + colb] = acc[m][j][reg];
            }
        }
    }
}

extern "C" void kernel_launch(void* const* d_in, const int* in_sizes, int n_in,
                              void* d_out, int out_size, void* d_ws, size_t ws_size,
                              hipStream_t stream) {
    const float* x          = (const float*)d_in[0];
    const float* y          = (const float*)d_in[1];
    const float* weight     = (const float*)d_in[2];
    const float* fc_w1      = (const float*)d_in[3];
    const float* fc_b1      = (const float*)d_in[4];
    const float* fc_prelu   = (const float*)d_in[5];
    const float* fc_w2      = (const float*)d_in[6];
    const float* fc_b2      = (const float*)d_in[7];
    const float* bias_w1    = (const float*)d_in[8];
    const float* bias_b1    = (const float*)d_in[9];
    const float* bias_prelu = (const float*)d_in[10];
    const float* bias_w2    = (const float*)d_in[11];
    const float* bias_b2    = (const float*)d_in[12];
    float* out = (float*)d_out;

    unsigned short* w_bf = (unsigned short*)d_ws;                       // 589824 B
    float* bvec = (float*)((char*)d_ws + (size_t)NB * 9 * 64 * 64 * 2); // 2048 B

    hipLaunchKernelGGL(mlp_kernel, dim3(17, 8), dim3(256), 0, stream,
                       y, weight, fc_w1, fc_b1, fc_prelu, fc_w2, fc_b2,
                       bias_w1, bias_b1, bias_prelu, bias_w2, bias_b2, w_bf, bvec);
    hipLaunchKernelGGL(conv_kernel, dim3(512), dim3(1024), 0, stream,
                       x, w_bf, bvec, out);
}